// Round 1
// baseline (415.743 us; speedup 1.0000x reference)
//
#include <hip/hip_runtime.h>

// 3-layer GCN + mean pool. bf16 storage / MFMA GEMM / fp32 accumulate.
// R15: source-window phased gather (cache-blocked SpMM).
//  - CSR rows sorted by src (k_sortrows, insertion sort, avg deg 3)
//  - fused kernels walk edges in 4MB source windows with per-phase
//    block barrier -> active gather window stays IC-resident, kills
//    the ~43MB/dispatch IC re-fetch + moves random service HBM->IC.
//  - everything else unchanged from R14 (dispatch-dieted prep/scan).

#define DIN 30
#define HD  128

typedef __attribute__((ext_vector_type(8))) short v8s;
typedef __attribute__((ext_vector_type(4))) float v4f;

static __device__ __forceinline__ unsigned short f2bf(float f) {
  unsigned int u = __float_as_uint(f);
  u += 0x7fffu + ((u >> 16) & 1u);   // RNE
  return (unsigned short)(u >> 16);
}
static __device__ __forceinline__ float bf2f(unsigned short s) {
  return __uint_as_float(((unsigned int)s) << 16);
}
static __device__ __forceinline__ float bflo(unsigned int u) {
  return __uint_as_float(u << 16);
}
static __device__ __forceinline__ float bfhi(unsigned int u) {
  return __uint_as_float(u & 0xffff0000u);
}

// ---------------- preprocessing ----------------
// degree + edge-order (position of edge within its destination's bucket)
__global__ void k_degree(const int* __restrict__ dst, int* __restrict__ deg,
                         int* __restrict__ eord, int E) {
  int e = blockIdx.x * blockDim.x + threadIdx.x;
  if (e < E) eord[e] = atomicAdd(&deg[dst[e]], 1);
}

// single-dispatch exclusive scan (decoupled lookback, flag bit 31) + dinv.
// scanbuf[NB] must be zeroed. 256 threads x 4 elems per block.
__global__ void k_scan(const int* __restrict__ deg, int* __restrict__ scanbuf,
                       int* __restrict__ rowptr, float* __restrict__ dinv, int N) {
  __shared__ int s[256];
  __shared__ int sbase;
  int bid = blockIdx.x, tid = threadIdx.x;
  int base = bid * 1024 + tid * 4;
  int v[4]; int t = 0;
#pragma unroll
  for (int j = 0; j < 4; ++j) { int idx = base + j; v[j] = (idx < N) ? deg[idx] : 0; t += v[j]; }
  s[tid] = t; __syncthreads();
  for (int d = 1; d < 256; d <<= 1) {
    int u = (tid >= d) ? s[tid - d] : 0;
    __syncthreads();
    s[tid] += u;
    __syncthreads();
  }
  int myexcl = s[tid] - t;           // exclusive prefix within block
  int blocktotal = s[255];
  if (tid == 0) atomicExch(&scanbuf[bid], blocktotal | 0x80000000);

  // parallel lookback: threads spin on predecessor flags
  int pre = 0;
  for (int p = tid; p < bid; p += 256) {
    int val;
    do { val = atomicAdd(&scanbuf[p], 0); } while (!(val & 0x80000000));
    pre += val & 0x7fffffff;
  }
  __syncthreads();                   // s[] free for reuse
  s[tid] = pre; __syncthreads();
  for (int d = 128; d > 0; d >>= 1) { if (tid < d) s[tid] += s[tid + d]; __syncthreads(); }
  if (tid == 0) sbase = s[0];
  __syncthreads();

  int run = sbase + myexcl;
#pragma unroll
  for (int j = 0; j < 4; ++j) {
    int idx = base + j;
    if (idx < N) {
      rowptr[idx] = run;
      dinv[idx] = rsqrtf((float)(1 + v[j]));
    }
    run += v[j];
    if (idx == N - 1) rowptr[N] = run;
  }
}

// fragment-major weight pack helper
static __device__ __forceinline__ void wtf_one(const float* __restrict__ W,
                                               unsigned short* __restrict__ WTF,
                                               int idx, int Kreal, int KK) {
  int j = idx & 7;
  int c = idx >> 3;
  int l15 = c & 15;
  int quad = (c >> 4) & 3;
  int kk = (c >> 6) % KK;
  int t = c / (64 * KK);
  int k = kk * 32 + quad * 8 + j;
  int n = t * 16 + l15;
  WTF[idx] = (k < Kreal) ? f2bf(W[k * 128 + n]) : (unsigned short)0;
}

// merged prep: atomic-free CSR scatter | xcast | wtf | bounds | out-zero
__global__ void k_prep(const int* __restrict__ src, const int* __restrict__ dst,
                       const int* __restrict__ rowptr, const int* __restrict__ eord,
                       int* __restrict__ col, int E,
                       const float* __restrict__ x, const float* __restrict__ dinv,
                       unsigned short* __restrict__ xb, int N,
                       const float* __restrict__ W1, const float* __restrict__ W2,
                       const float* __restrict__ W3,
                       unsigned short* __restrict__ W1F, unsigned short* __restrict__ W2F,
                       unsigned short* __restrict__ W3F,
                       const int* __restrict__ batch, int* __restrict__ gstart, int G,
                       float* __restrict__ out,
                       int SB, int XB, int WB, int BB) {
  int blk = blockIdx.x;
  if (blk < SB) {
    int e = blk * 256 + threadIdx.x;
    if (e < E) col[rowptr[dst[e]] + eord[e]] = src[e];
  } else if (blk < SB + XB) {
    int idx = (blk - SB) * 256 + threadIdx.x;
    if (idx < N * 32) {
      int n = idx >> 5, f = idx & 31;
      float v = (f < DIN) ? x[(size_t)n * DIN + f] * dinv[n] : 0.f;
      xb[idx] = f2bf(v);
    }
  } else if (blk < SB + XB + WB) {
    int idx = (blk - SB - XB) * 256 + threadIdx.x;
    if (idx < 4096) wtf_one(W1, W1F, idx, DIN, 1);
    else if (idx < 20480) wtf_one(W2, W2F, idx - 4096, 128, 4);
    else if (idx < 36864) wtf_one(W3, W3F, idx - 20480, 128, 4);
  } else if (blk < SB + XB + WB + BB) {
    int i = (blk - SB - XB - WB) * 256 + threadIdx.x;
    if (i >= N) return;
    int b = batch[i];
    int prev = (i == 0) ? -1 : batch[i - 1];
    for (int g = prev + 1; g <= b; ++g) gstart[g] = i;
    if (i == N - 1)
      for (int g = b + 1; g <= G; ++g) gstart[g] = N;
  } else {
    // zero out[] : G*128 floats, float4 per thread
    int idx = (blk - SB - XB - WB - BB) * 256 + threadIdx.x;
    if (idx < G * 32)
      ((float4*)out)[idx] = make_float4(0.f, 0.f, 0.f, 0.f);
  }
}

// sort each CSR row by src so the fused gather can walk source windows.
// avg degree 3 (Poisson) -> global-memory insertion sort is fine.
__global__ void k_sortrows(const int* __restrict__ rowptr, int* __restrict__ col, int N) {
  int n = blockIdx.x * blockDim.x + threadIdx.x;
  if (n >= N) return;
  int e0 = rowptr[n], e1 = rowptr[n + 1];
  for (int i = e0 + 1; i < e1; ++i) {
    int v = col[i];
    int j = i - 1;
    while (j >= e0 && col[j] > v) { col[j + 1] = col[j]; --j; }
    col[j + 1] = v;
  }
}

// ---------------- fused aggregate + MFMA GEMM (layers 1,2) ----------------
template <int K>
__global__ __launch_bounds__(1024, 8) void k_fused(const unsigned short* __restrict__ hin,
                                                   const unsigned short* __restrict__ WTF,
                                                   const float* __restrict__ b,
                                                   const int* __restrict__ rowptr,
                                                   const int* __restrict__ col,
                                                   const float* __restrict__ dinv,
                                                   unsigned short* __restrict__ C, int N) {
  constexpr int KK = K / 32;
  constexpr int KP = (K == 128) ? 136 : 40;
  constexpr int CP = 132;
  constexpr int SMSZ = (64 * KP > 64 * CP) ? 64 * KP : 64 * CP;
  // 4MB source window: rows are 64B (K=32) or 256B (K=128)
  constexpr int WDW = (K == 32) ? 65536 : 16384;
  __shared__ __align__(16) unsigned short sm[SMSZ];

  int tid = threadIdx.x;
  int l16 = tid & 15;
  int nl = tid >> 4;
  int row0 = blockIdx.x * 64;
  int node = row0 + nl;

  // ---- phase 1: agg = dinv[node] * (sum h'[col] + h'[node]) into LDS ----
  // edges walked in ascending-src phases so the active gather window is
  // cache-resident; per-phase barrier keeps the whole block in one window.
  if (K == 32) {
    const unsigned int* hp = (const unsigned int*)hin;
    float a0 = 0.f, a1 = 0.f;
    int e = 0, e1 = 0;
    if (node < N) {
      unsigned int u = hp[(size_t)node * 16 + l16];
      a0 = bflo(u); a1 = bfhi(u);
      e = rowptr[node]; e1 = rowptr[node + 1];
    }
    int nc = (e < e1) ? col[e] : 0x7fffffff;
    for (int lim = WDW;; lim += WDW) {
      while (nc < lim) {
        unsigned int v0 = hp[(size_t)nc * 16 + l16];
        ++e;
        nc = (e < e1) ? col[e] : 0x7fffffff;
        a0 += bflo(v0); a1 += bfhi(v0);
      }
      if (lim >= N) break;
      __syncthreads();
    }
    if (node < N) {
      float di = dinv[node];
      a0 *= di; a1 *= di;
    }
    *(unsigned int*)&sm[nl * KP + l16 * 2] =
        (unsigned int)f2bf(a0) | ((unsigned int)f2bf(a1) << 16);
  } else {
    const uint4* hp = (const uint4*)hin;
    float a0 = 0.f, a1 = 0.f, a2 = 0.f, a3 = 0.f, a4 = 0.f, a5 = 0.f, a6 = 0.f, a7 = 0.f;
    int e = 0, e1 = 0;
    if (node < N) {
      uint4 u = hp[(size_t)node * 16 + l16];
      a0 = bflo(u.x); a1 = bfhi(u.x);
      a2 = bflo(u.y); a3 = bfhi(u.y);
      a4 = bflo(u.z); a5 = bfhi(u.z);
      a6 = bflo(u.w); a7 = bfhi(u.w);
      e = rowptr[node]; e1 = rowptr[node + 1];
    }
    int nc = (e < e1) ? col[e] : 0x7fffffff;
    for (int lim = WDW;; lim += WDW) {
      while (nc < lim) {
        uint4 v0 = hp[(size_t)nc * 16 + l16];
        ++e;
        nc = (e < e1) ? col[e] : 0x7fffffff;
        a0 += bflo(v0.x); a1 += bfhi(v0.x);
        a2 += bflo(v0.y); a3 += bfhi(v0.y);
        a4 += bflo(v0.z); a5 += bfhi(v0.z);
        a6 += bflo(v0.w); a7 += bfhi(v0.w);
      }
      if (lim >= N) break;
      __syncthreads();
    }
    if (node < N) {
      float di = dinv[node];
      a0 *= di; a1 *= di; a2 *= di; a3 *= di;
      a4 *= di; a5 *= di; a6 *= di; a7 *= di;
    }
    uint4 o;
    o.x = (unsigned int)f2bf(a0) | ((unsigned int)f2bf(a1) << 16);
    o.y = (unsigned int)f2bf(a2) | ((unsigned int)f2bf(a3) << 16);
    o.z = (unsigned int)f2bf(a4) | ((unsigned int)f2bf(a5) << 16);
    o.w = (unsigned int)f2bf(a6) | ((unsigned int)f2bf(a7) << 16);
    *(uint4*)&sm[nl * KP + l16 * 8] = o;
  }
  __syncthreads();

  // ---- phase 2: A-frags from LDS; 16 waves = 4 row-tiles x 4 t-pairs ----
  int wv = tid >> 6, lane = tid & 63, quad = lane >> 4, l15 = lane & 15;
  int rt = wv & 3, tp = wv >> 2;
  v8s af[KK];
#pragma unroll
  for (int kk = 0; kk < KK; ++kk)
    af[kk] = *(const v8s*)&sm[(rt * 16 + l15) * KP + kk * 32 + quad * 8];
  __syncthreads();

  // hoisted next-layer pre-scale: dinv for this lane's 4 output rows
  int crow0 = row0 + rt * 16 + quad * 4;
  float dr[4];
  if (crow0 + 3 < N) {
    float4 d4 = *(const float4*)&dinv[crow0];
    dr[0] = d4.x; dr[1] = d4.y; dr[2] = d4.z; dr[3] = d4.w;
  } else {
#pragma unroll
    for (int i = 0; i < 4; ++i) dr[i] = (crow0 + i < N) ? dinv[crow0 + i] : 0.f;
  }

#pragma unroll
  for (int tt = 0; tt < 2; ++tt) {
    int t = tp * 2 + tt;
    v4f acc = {0.f, 0.f, 0.f, 0.f};
#pragma unroll
    for (int kk = 0; kk < KK; ++kk) {
      v8s bf = *(const v8s*)(WTF + (size_t)(((t * KK + kk) * 4 + quad) * 16 + l15) * 8);
      acc = __builtin_amdgcn_mfma_f32_16x16x32_bf16(af[kk], bf, acc, 0, 0, 0);
    }
    float bias = b[t * 16 + l15];
#pragma unroll
    for (int i = 0; i < 4; ++i) {
      float o = fmaxf(acc[i] + bias, 0.f) * dr[i];
      sm[(rt * 16 + quad * 4 + i) * CP + t * 16 + l15] = f2bf(o);
    }
  }
  __syncthreads();

  // ---- phase 3: coalesced C store ----
#pragma unroll
  for (int j = 0; j < 2; ++j) {
    int linear = j * 1024 + tid;
    int r = linear >> 5, ch = linear & 31;
    uint2 v = *(const uint2*)&sm[r * CP + ch * 4];
    int row = row0 + r;
    if (row < N) ((uint2*)C)[(size_t)row * 32 + ch] = v;
  }
}

// ---------------- layer 3: fused aggregate + GEMM + pool-atomics ----------------
__global__ __launch_bounds__(1024, 8) void k_fused_pool(const unsigned short* __restrict__ hin,
                                                        const unsigned short* __restrict__ WTF,
                                                        const float* __restrict__ b,
                                                        const int* __restrict__ rowptr,
                                                        const int* __restrict__ col,
                                                        const float* __restrict__ dinv,
                                                        const int* __restrict__ batch,
                                                        float* __restrict__ out, int N) {
  constexpr int KK = 4, KP = 136, CP = 132;
  constexpr int SMSZ = 64 * KP;
  constexpr int WDW = 16384;
  __shared__ __align__(16) unsigned short sm[SMSZ];
  __shared__ int sbatch[64];

  int tid = threadIdx.x;
  int l16 = tid & 15;
  int nl = tid >> 4;
  int row0 = blockIdx.x * 64;
  int node = row0 + nl;

  if (tid < 64) sbatch[tid] = (row0 + tid < N) ? batch[row0 + tid] : -1;

  // ---- phase 1 (source-window phased, as in k_fused) ----
  {
    const uint4* hp = (const uint4*)hin;
    float a0 = 0.f, a1 = 0.f, a2 = 0.f, a3 = 0.f, a4 = 0.f, a5 = 0.f, a6 = 0.f, a7 = 0.f;
    int e = 0, e1 = 0;
    if (node < N) {
      uint4 u = hp[(size_t)node * 16 + l16];
      a0 = bflo(u.x); a1 = bfhi(u.x);
      a2 = bflo(u.y); a3 = bfhi(u.y);
      a4 = bflo(u.z); a5 = bfhi(u.z);
      a6 = bflo(u.w); a7 = bfhi(u.w);
      e = rowptr[node]; e1 = rowptr[node + 1];
    }
    int nc = (e < e1) ? col[e] : 0x7fffffff;
    for (int lim = WDW;; lim += WDW) {
      while (nc < lim) {
        uint4 v0 = hp[(size_t)nc * 16 + l16];
        ++e;
        nc = (e < e1) ? col[e] : 0x7fffffff;
        a0 += bflo(v0.x); a1 += bfhi(v0.x);
        a2 += bflo(v0.y); a3 += bfhi(v0.y);
        a4 += bflo(v0.z); a5 += bfhi(v0.z);
        a6 += bflo(v0.w); a7 += bfhi(v0.w);
      }
      if (lim >= N) break;
      __syncthreads();
    }
    if (node < N) {
      float di = dinv[node];
      a0 *= di; a1 *= di; a2 *= di; a3 *= di;
      a4 *= di; a5 *= di; a6 *= di; a7 *= di;
    }
    uint4 o;
    o.x = (unsigned int)f2bf(a0) | ((unsigned int)f2bf(a1) << 16);
    o.y = (unsigned int)f2bf(a2) | ((unsigned int)f2bf(a3) << 16);
    o.z = (unsigned int)f2bf(a4) | ((unsigned int)f2bf(a5) << 16);
    o.w = (unsigned int)f2bf(a6) | ((unsigned int)f2bf(a7) << 16);
    *(uint4*)&sm[nl * KP + l16 * 8] = o;
  }
  __syncthreads();

  // ---- phase 2 (no epilogue scaling: pool needs raw h3) ----
  int wv = tid >> 6, lane = tid & 63, quad = lane >> 4, l15 = lane & 15;
  int rt = wv & 3, tp = wv >> 2;
  v8s af[KK];
#pragma unroll
  for (int kk = 0; kk < KK; ++kk)
    af[kk] = *(const v8s*)&sm[(rt * 16 + l15) * KP + kk * 32 + quad * 8];
  __syncthreads();

#pragma unroll
  for (int tt = 0; tt < 2; ++tt) {
    int t = tp * 2 + tt;
    v4f acc = {0.f, 0.f, 0.f, 0.f};
#pragma unroll
    for (int kk = 0; kk < KK; ++kk) {
      v8s bf = *(const v8s*)(WTF + (size_t)(((t * KK + kk) * 4 + quad) * 16 + l15) * 8);
      acc = __builtin_amdgcn_mfma_f32_16x16x32_bf16(af[kk], bf, acc, 0, 0, 0);
    }
    float bias = b[t * 16 + l15];
#pragma unroll
    for (int i = 0; i < 4; ++i) {
      float o = fmaxf(acc[i] + bias, 0.f);
      sm[(rt * 16 + quad * 4 + i) * CP + t * 16 + l15] = f2bf(o);
    }
  }
  __syncthreads();

  // ---- phase 3: segment-sum the 64 sorted rows, atomicAdd partials ----
  int f = tid & 127;
  int grp = tid >> 7;
  float run = 0.f;
  int cur = -1;
#pragma unroll
  for (int j = 0; j < 8; ++j) {
    int r = grp * 8 + j;
    int g = sbatch[r];
    if (g != cur) {
      if (cur >= 0) atomicAdd(&out[(size_t)cur * 128 + f], run);
      run = 0.f; cur = g;
    }
    if (g >= 0) run += bf2f(sm[r * CP + f]);
  }
  if (cur >= 0) atomicAdd(&out[(size_t)cur * 128 + f], run);
}

// divide pooled sums by segment counts
__global__ void k_finalize(float* __restrict__ out, const int* __restrict__ gstart, int G) {
  int idx = blockIdx.x * blockDim.x + threadIdx.x;
  if (idx >= G * 128) return;
  int g = idx >> 7;
  float cnt = (float)(gstart[g + 1] - gstart[g]);
  out[idx] = out[idx] / fmaxf(cnt, 1.f);
}

extern "C" void kernel_launch(void* const* d_in, const int* in_sizes, int n_in,
                              void* d_out, int out_size, void* d_ws, size_t ws_size,
                              hipStream_t stream) {
  const float* x  = (const float*)d_in[0];
  const int* ei   = (const int*)d_in[1];
  const int* batch = (const int*)d_in[2];
  const float* W1 = (const float*)d_in[3];
  const float* b1 = (const float*)d_in[4];
  const float* W2 = (const float*)d_in[5];
  const float* b2 = (const float*)d_in[6];
  const float* W3 = (const float*)d_in[7];
  const float* b3 = (const float*)d_in[8];
  float* out = (float*)d_out;
  int N = in_sizes[2];
  int E = in_sizes[1] / 2;
  int G = out_size / HD;
  const int* src = ei;
  const int* dst = ei + E;

  size_t off = 0;
  char* ws = (char*)d_ws;
  auto alloc = [&](size_t bytes) -> void* {
    void* p = ws + off;
    off += (bytes + 255) & ~(size_t)255;
    return p;
  };
  int nb1024 = (N + 1023) / 1024;
  int*   deg     = (int*)alloc((size_t)N * 4);        // N*4 is 256-aligned for N=200000
  int*   scanbuf = (int*)alloc((size_t)nb1024 * 4);   // contiguous after deg -> one memset
  float* dinv    = (float*)alloc((size_t)N * 4);
  int*   rowptr  = (int*)alloc((size_t)(N + 1) * 4);
  int*   eord    = (int*)alloc((size_t)E * 4);
  int*   col     = (int*)alloc((size_t)E * 4);
  int*   gstart  = (int*)alloc((size_t)(G + 1) * 4);
  unsigned short* xb  = (unsigned short*)alloc((size_t)N * 32 * 2);
  unsigned short* hA  = (unsigned short*)alloc((size_t)N * HD * 2);
  unsigned short* hB  = (unsigned short*)alloc((size_t)N * HD * 2);
  unsigned short* W1F = (unsigned short*)alloc(4096 * 2);
  unsigned short* W2F = (unsigned short*)alloc(16384 * 2);
  unsigned short* W3F = (unsigned short*)alloc(16384 * 2);
  (void)ws_size; (void)n_in;

  size_t zbytes = (size_t)((char*)dinv - (char*)deg);  // deg + scanbuf region
  hipMemsetAsync(deg, 0, zbytes, stream);
  k_degree<<<(E + 255) / 256, 256, 0, stream>>>(dst, deg, eord, E);
  k_scan<<<nb1024, 256, 0, stream>>>(deg, scanbuf, rowptr, dinv, N);

  int SB = (E + 255) / 256;
  int XB = (N * 32 + 255) / 256;
  int WB = 144;
  int BB = (N + 255) / 256;
  int ZB = (G * 32 + 255) / 256;   // out zero, float4/thread
  k_prep<<<SB + XB + WB + BB + ZB, 256, 0, stream>>>(src, dst, rowptr, eord, col, E,
                                                     x, dinv, xb, N,
                                                     W1, W2, W3, W1F, W2F, W3F,
                                                     batch, gstart, G, out,
                                                     SB, XB, WB, BB);
  k_sortrows<<<(N + 255) / 256, 256, 0, stream>>>(rowptr, col, N);

  int fusedBlocks = (N + 63) / 64;
  k_fused<32><<<fusedBlocks, 1024, 0, stream>>>(xb, W1F, b1, rowptr, col, dinv, hA, N);
  k_fused<128><<<fusedBlocks, 1024, 0, stream>>>(hA, W2F, b2, rowptr, col, dinv, hB, N);
  k_fused_pool<<<fusedBlocks, 1024, 0, stream>>>(hB, W3F, b3, rowptr, col, dinv, batch, out, N);
  k_finalize<<<(G * 128 + 255) / 256, 256, 0, stream>>>(out, gstart, G);
}

// Round 2
// 295.082 us; speedup vs baseline: 1.4089x; 1.4089x over previous
//
#include <hip/hip_runtime.h>

// 3-layer GCN + mean pool. MFMA GEMM / fp32 accumulate.
// R16: revert R15 phasing (failed: per-block windows can't make global
// locality; FETCH unchanged, dur 62->110us). New lever: inter-layer
// tables hA/hB stored as uint8 + per-row fp32 scale (all values are
// post-ReLU >= 0). Row = 128B = ONE 128B line per random gather
// (bf16 was 256B = two lines). Scale array (800KB) stays L2-resident.
// uint8 per-row quant error ~ rowmax/510 ~= bf16 grade.
//  - k_fused epilogue: per-row max (shfl over 16 lanes) -> uint8 pack
//  - k_fused<128>/k_fused_pool gather: uint2 row + scale, cvt_ubyte+fmac
//  - layer-1 xb stays bf16 (64B rows already single-line)

#define DIN 30
#define HD  128

typedef __attribute__((ext_vector_type(8))) short v8s;
typedef __attribute__((ext_vector_type(4))) float v4f;

static __device__ __forceinline__ unsigned short f2bf(float f) {
  unsigned int u = __float_as_uint(f);
  u += 0x7fffu + ((u >> 16) & 1u);   // RNE
  return (unsigned short)(u >> 16);
}
static __device__ __forceinline__ float bf2f(unsigned short s) {
  return __uint_as_float(((unsigned int)s) << 16);
}
static __device__ __forceinline__ float bflo(unsigned int u) {
  return __uint_as_float(u << 16);
}
static __device__ __forceinline__ float bfhi(unsigned int u) {
  return __uint_as_float(u & 0xffff0000u);
}

// dequant-accumulate 8 uint8 lanes' worth: a_j += s * byte_j(v)
#define ACC8(v, s)                                            \
  {                                                           \
    a0 += (s) * (float)((v).x & 0xffu);                       \
    a1 += (s) * (float)(((v).x >> 8) & 0xffu);                \
    a2 += (s) * (float)(((v).x >> 16) & 0xffu);               \
    a3 += (s) * (float)((v).x >> 24);                         \
    a4 += (s) * (float)((v).y & 0xffu);                       \
    a5 += (s) * (float)(((v).y >> 8) & 0xffu);                \
    a6 += (s) * (float)(((v).y >> 16) & 0xffu);               \
    a7 += (s) * (float)((v).y >> 24);                         \
  }

// ---------------- preprocessing ----------------
__global__ void k_degree(const int* __restrict__ dst, int* __restrict__ deg,
                         int* __restrict__ eord, int E) {
  int e = blockIdx.x * blockDim.x + threadIdx.x;
  if (e < E) eord[e] = atomicAdd(&deg[dst[e]], 1);
}

// single-dispatch exclusive scan (decoupled lookback, flag bit 31) + dinv.
__global__ void k_scan(const int* __restrict__ deg, int* __restrict__ scanbuf,
                       int* __restrict__ rowptr, float* __restrict__ dinv, int N) {
  __shared__ int s[256];
  __shared__ int sbase;
  int bid = blockIdx.x, tid = threadIdx.x;
  int base = bid * 1024 + tid * 4;
  int v[4]; int t = 0;
#pragma unroll
  for (int j = 0; j < 4; ++j) { int idx = base + j; v[j] = (idx < N) ? deg[idx] : 0; t += v[j]; }
  s[tid] = t; __syncthreads();
  for (int d = 1; d < 256; d <<= 1) {
    int u = (tid >= d) ? s[tid - d] : 0;
    __syncthreads();
    s[tid] += u;
    __syncthreads();
  }
  int myexcl = s[tid] - t;
  int blocktotal = s[255];
  if (tid == 0) atomicExch(&scanbuf[bid], blocktotal | 0x80000000);

  int pre = 0;
  for (int p = tid; p < bid; p += 256) {
    int val;
    do { val = atomicAdd(&scanbuf[p], 0); } while (!(val & 0x80000000));
    pre += val & 0x7fffffff;
  }
  __syncthreads();
  s[tid] = pre; __syncthreads();
  for (int d = 128; d > 0; d >>= 1) { if (tid < d) s[tid] += s[tid + d]; __syncthreads(); }
  if (tid == 0) sbase = s[0];
  __syncthreads();

  int run = sbase + myexcl;
#pragma unroll
  for (int j = 0; j < 4; ++j) {
    int idx = base + j;
    if (idx < N) {
      rowptr[idx] = run;
      dinv[idx] = rsqrtf((float)(1 + v[j]));
    }
    run += v[j];
    if (idx == N - 1) rowptr[N] = run;
  }
}

// fragment-major weight pack helper
static __device__ __forceinline__ void wtf_one(const float* __restrict__ W,
                                               unsigned short* __restrict__ WTF,
                                               int idx, int Kreal, int KK) {
  int j = idx & 7;
  int c = idx >> 3;
  int l15 = c & 15;
  int quad = (c >> 4) & 3;
  int kk = (c >> 6) % KK;
  int t = c / (64 * KK);
  int k = kk * 32 + quad * 8 + j;
  int n = t * 16 + l15;
  WTF[idx] = (k < Kreal) ? f2bf(W[k * 128 + n]) : (unsigned short)0;
}

// merged prep: atomic-free CSR scatter | xcast | wtf | bounds | out-zero
__global__ void k_prep(const int* __restrict__ src, const int* __restrict__ dst,
                       const int* __restrict__ rowptr, const int* __restrict__ eord,
                       int* __restrict__ col, int E,
                       const float* __restrict__ x, const float* __restrict__ dinv,
                       unsigned short* __restrict__ xb, int N,
                       const float* __restrict__ W1, const float* __restrict__ W2,
                       const float* __restrict__ W3,
                       unsigned short* __restrict__ W1F, unsigned short* __restrict__ W2F,
                       unsigned short* __restrict__ W3F,
                       const int* __restrict__ batch, int* __restrict__ gstart, int G,
                       float* __restrict__ out,
                       int SB, int XB, int WB, int BB) {
  int blk = blockIdx.x;
  if (blk < SB) {
    int e = blk * 256 + threadIdx.x;
    if (e < E) col[rowptr[dst[e]] + eord[e]] = src[e];
  } else if (blk < SB + XB) {
    int idx = (blk - SB) * 256 + threadIdx.x;
    if (idx < N * 32) {
      int n = idx >> 5, f = idx & 31;
      float v = (f < DIN) ? x[(size_t)n * DIN + f] * dinv[n] : 0.f;
      xb[idx] = f2bf(v);
    }
  } else if (blk < SB + XB + WB) {
    int idx = (blk - SB - XB) * 256 + threadIdx.x;
    if (idx < 4096) wtf_one(W1, W1F, idx, DIN, 1);
    else if (idx < 20480) wtf_one(W2, W2F, idx - 4096, 128, 4);
    else if (idx < 36864) wtf_one(W3, W3F, idx - 20480, 128, 4);
  } else if (blk < SB + XB + WB + BB) {
    int i = (blk - SB - XB - WB) * 256 + threadIdx.x;
    if (i >= N) return;
    int b = batch[i];
    int prev = (i == 0) ? -1 : batch[i - 1];
    for (int g = prev + 1; g <= b; ++g) gstart[g] = i;
    if (i == N - 1)
      for (int g = b + 1; g <= G; ++g) gstart[g] = N;
  } else {
    int idx = (blk - SB - XB - WB - BB) * 256 + threadIdx.x;
    if (idx < G * 32)
      ((float4*)out)[idx] = make_float4(0.f, 0.f, 0.f, 0.f);
  }
}

// ---------------- fused aggregate + MFMA GEMM (layers 1,2) ----------------
// K=32 : input = bf16 xb (64B rows). K=128 : input = uint8 rows + scale.
// Output: uint8 rows (128B) + per-row fp32 scale.
template <int K>
__global__ __launch_bounds__(1024, 8) void k_fused(const void* __restrict__ hin,
                                                   const float* __restrict__ hscale,
                                                   const unsigned short* __restrict__ WTF,
                                                   const float* __restrict__ b,
                                                   const int* __restrict__ rowptr,
                                                   const int* __restrict__ col,
                                                   const float* __restrict__ dinv,
                                                   unsigned char* __restrict__ Cq,
                                                   float* __restrict__ Cs, int N) {
  constexpr int KK = K / 32;
  constexpr int KP = (K == 128) ? 136 : 40;
  constexpr int CP = 132;
  constexpr int SMSZ = (64 * KP > 64 * CP) ? 64 * KP : 64 * CP;
  __shared__ __align__(16) unsigned short sm[SMSZ];

  int tid = threadIdx.x;
  int l16 = tid & 15;
  int nl = tid >> 4;
  int row0 = blockIdx.x * 64;
  int node = row0 + nl;

  // ---- phase 1: agg = dinv[node] * (sum h'[col] + h'[node]) into LDS ----
  if constexpr (K == 32) {
    const unsigned int* hp = (const unsigned int*)hin;
    float a0 = 0.f, a1 = 0.f;
    if (node < N) {
      unsigned int u = hp[(size_t)node * 16 + l16];
      a0 = bflo(u); a1 = bfhi(u);
      int e0 = rowptr[node], e1 = rowptr[node + 1];
      int e = e0;
      for (; e + 2 <= e1; e += 2) {
        int c0 = col[e], c1 = col[e + 1];
        unsigned int v0 = hp[(size_t)c0 * 16 + l16];
        unsigned int v1 = hp[(size_t)c1 * 16 + l16];
        a0 += bflo(v0); a1 += bfhi(v0);
        a0 += bflo(v1); a1 += bfhi(v1);
      }
      if (e < e1) {
        unsigned int v0 = hp[(size_t)col[e] * 16 + l16];
        a0 += bflo(v0); a1 += bfhi(v0);
      }
      float di = dinv[node];
      a0 *= di; a1 *= di;
    }
    *(unsigned int*)&sm[nl * KP + l16 * 2] =
        (unsigned int)f2bf(a0) | ((unsigned int)f2bf(a1) << 16);
  } else {
    const uint2* hq = (const uint2*)hin;
    float a0 = 0.f, a1 = 0.f, a2 = 0.f, a3 = 0.f, a4 = 0.f, a5 = 0.f, a6 = 0.f, a7 = 0.f;
    if (node < N) {
      uint2 u = hq[(size_t)node * 16 + l16];
      float ss = hscale[node];
      ACC8(u, ss);
      int e0 = rowptr[node], e1 = rowptr[node + 1];
      int e = e0;
      for (; e + 2 <= e1; e += 2) {
        int c0 = col[e], c1 = col[e + 1];
        uint2 v0 = hq[(size_t)c0 * 16 + l16];
        uint2 v1 = hq[(size_t)c1 * 16 + l16];
        float s0 = hscale[c0];
        float s1 = hscale[c1];
        ACC8(v0, s0);
        ACC8(v1, s1);
      }
      if (e < e1) {
        int c0 = col[e];
        uint2 v0 = hq[(size_t)c0 * 16 + l16];
        float s0 = hscale[c0];
        ACC8(v0, s0);
      }
      float di = dinv[node];
      a0 *= di; a1 *= di; a2 *= di; a3 *= di;
      a4 *= di; a5 *= di; a6 *= di; a7 *= di;
    }
    uint4 o;
    o.x = (unsigned int)f2bf(a0) | ((unsigned int)f2bf(a1) << 16);
    o.y = (unsigned int)f2bf(a2) | ((unsigned int)f2bf(a3) << 16);
    o.z = (unsigned int)f2bf(a4) | ((unsigned int)f2bf(a5) << 16);
    o.w = (unsigned int)f2bf(a6) | ((unsigned int)f2bf(a7) << 16);
    *(uint4*)&sm[nl * KP + l16 * 8] = o;
  }
  __syncthreads();

  // ---- phase 2: A-frags from LDS; 16 waves = 4 row-tiles x 4 t-pairs ----
  int wv = tid >> 6, lane = tid & 63, quad = lane >> 4, l15 = lane & 15;
  int rt = wv & 3, tp = wv >> 2;
  v8s af[KK];
#pragma unroll
  for (int kk = 0; kk < KK; ++kk)
    af[kk] = *(const v8s*)&sm[(rt * 16 + l15) * KP + kk * 32 + quad * 8];
  __syncthreads();

  // hoisted next-layer pre-scale: dinv for this lane's 4 output rows
  int crow0 = row0 + rt * 16 + quad * 4;
  float dr[4];
  if (crow0 + 3 < N) {
    float4 d4 = *(const float4*)&dinv[crow0];
    dr[0] = d4.x; dr[1] = d4.y; dr[2] = d4.z; dr[3] = d4.w;
  } else {
#pragma unroll
    for (int i = 0; i < 4; ++i) dr[i] = (crow0 + i < N) ? dinv[crow0 + i] : 0.f;
  }

#pragma unroll
  for (int tt = 0; tt < 2; ++tt) {
    int t = tp * 2 + tt;
    v4f acc = {0.f, 0.f, 0.f, 0.f};
#pragma unroll
    for (int kk = 0; kk < KK; ++kk) {
      v8s bf = *(const v8s*)(WTF + (size_t)(((t * KK + kk) * 4 + quad) * 16 + l15) * 8);
      acc = __builtin_amdgcn_mfma_f32_16x16x32_bf16(af[kk], bf, acc, 0, 0, 0);
    }
    float bias = b[t * 16 + l15];
#pragma unroll
    for (int i = 0; i < 4; ++i) {
      float o = fmaxf(acc[i] + bias, 0.f) * dr[i];
      sm[(rt * 16 + quad * 4 + i) * CP + t * 16 + l15] = f2bf(o);
    }
  }
  __syncthreads();

  // ---- phase 3: per-row uint8 quantize + coalesced store ----
  // 64 groups of 16 lanes; group nl owns row nl (8 values per lane).
  {
    uint4 u = *(const uint4*)&sm[nl * CP + l16 * 8];
    float f0 = bflo(u.x), f1 = bfhi(u.x), f2 = bflo(u.y), f3 = bfhi(u.y);
    float f4 = bflo(u.z), f5 = bfhi(u.z), f6 = bflo(u.w), f7 = bfhi(u.w);
    float m = fmaxf(fmaxf(fmaxf(f0, f1), fmaxf(f2, f3)),
                    fmaxf(fmaxf(f4, f5), fmaxf(f6, f7)));
    m = fmaxf(m, __shfl_xor(m, 1));
    m = fmaxf(m, __shfl_xor(m, 2));
    m = fmaxf(m, __shfl_xor(m, 4));
    m = fmaxf(m, __shfl_xor(m, 8));
    float inv = (m > 0.f) ? 255.f / m : 0.f;
    unsigned q0 = (unsigned)__float2int_rn(fminf(f0 * inv, 255.f));
    unsigned q1 = (unsigned)__float2int_rn(fminf(f1 * inv, 255.f));
    unsigned q2 = (unsigned)__float2int_rn(fminf(f2 * inv, 255.f));
    unsigned q3 = (unsigned)__float2int_rn(fminf(f3 * inv, 255.f));
    unsigned q4 = (unsigned)__float2int_rn(fminf(f4 * inv, 255.f));
    unsigned q5 = (unsigned)__float2int_rn(fminf(f5 * inv, 255.f));
    unsigned q6 = (unsigned)__float2int_rn(fminf(f6 * inv, 255.f));
    unsigned q7 = (unsigned)__float2int_rn(fminf(f7 * inv, 255.f));
    uint2 o;
    o.x = q0 | (q1 << 8) | (q2 << 16) | (q3 << 24);
    o.y = q4 | (q5 << 8) | (q6 << 16) | (q7 << 24);
    int row = row0 + nl;
    if (row < N) {
      ((uint2*)Cq)[(size_t)row * 16 + l16] = o;
      if (l16 == 0) Cs[row] = m * (1.f / 255.f);
    }
  }
}

// ---------------- layer 3: fused aggregate + GEMM + pool-atomics ----------------
__global__ __launch_bounds__(1024, 8) void k_fused_pool(const unsigned char* __restrict__ hin,
                                                        const float* __restrict__ hscale,
                                                        const unsigned short* __restrict__ WTF,
                                                        const float* __restrict__ b,
                                                        const int* __restrict__ rowptr,
                                                        const int* __restrict__ col,
                                                        const float* __restrict__ dinv,
                                                        const int* __restrict__ batch,
                                                        float* __restrict__ out, int N) {
  constexpr int KK = 4, KP = 136, CP = 132;
  constexpr int SMSZ = 64 * KP;
  __shared__ __align__(16) unsigned short sm[SMSZ];
  __shared__ int sbatch[64];

  int tid = threadIdx.x;
  int l16 = tid & 15;
  int nl = tid >> 4;
  int row0 = blockIdx.x * 64;
  int node = row0 + nl;

  if (tid < 64) sbatch[tid] = (row0 + tid < N) ? batch[row0 + tid] : -1;

  // ---- phase 1: uint8 dequant gather ----
  {
    const uint2* hq = (const uint2*)hin;
    float a0 = 0.f, a1 = 0.f, a2 = 0.f, a3 = 0.f, a4 = 0.f, a5 = 0.f, a6 = 0.f, a7 = 0.f;
    if (node < N) {
      uint2 u = hq[(size_t)node * 16 + l16];
      float ss = hscale[node];
      ACC8(u, ss);
      int e0 = rowptr[node], e1 = rowptr[node + 1];
      int e = e0;
      for (; e + 2 <= e1; e += 2) {
        int c0 = col[e], c1 = col[e + 1];
        uint2 v0 = hq[(size_t)c0 * 16 + l16];
        uint2 v1 = hq[(size_t)c1 * 16 + l16];
        float s0 = hscale[c0];
        float s1 = hscale[c1];
        ACC8(v0, s0);
        ACC8(v1, s1);
      }
      if (e < e1) {
        int c0 = col[e];
        uint2 v0 = hq[(size_t)c0 * 16 + l16];
        float s0 = hscale[c0];
        ACC8(v0, s0);
      }
      float di = dinv[node];
      a0 *= di; a1 *= di; a2 *= di; a3 *= di;
      a4 *= di; a5 *= di; a6 *= di; a7 *= di;
    }
    uint4 o;
    o.x = (unsigned int)f2bf(a0) | ((unsigned int)f2bf(a1) << 16);
    o.y = (unsigned int)f2bf(a2) | ((unsigned int)f2bf(a3) << 16);
    o.z = (unsigned int)f2bf(a4) | ((unsigned int)f2bf(a5) << 16);
    o.w = (unsigned int)f2bf(a6) | ((unsigned int)f2bf(a7) << 16);
    *(uint4*)&sm[nl * KP + l16 * 8] = o;
  }
  __syncthreads();

  // ---- phase 2 (no epilogue scaling: pool needs raw h3) ----
  int wv = tid >> 6, lane = tid & 63, quad = lane >> 4, l15 = lane & 15;
  int rt = wv & 3, tp = wv >> 2;
  v8s af[KK];
#pragma unroll
  for (int kk = 0; kk < KK; ++kk)
    af[kk] = *(const v8s*)&sm[(rt * 16 + l15) * KP + kk * 32 + quad * 8];
  __syncthreads();

#pragma unroll
  for (int tt = 0; tt < 2; ++tt) {
    int t = tp * 2 + tt;
    v4f acc = {0.f, 0.f, 0.f, 0.f};
#pragma unroll
    for (int kk = 0; kk < KK; ++kk) {
      v8s bf = *(const v8s*)(WTF + (size_t)(((t * KK + kk) * 4 + quad) * 16 + l15) * 8);
      acc = __builtin_amdgcn_mfma_f32_16x16x32_bf16(af[kk], bf, acc, 0, 0, 0);
    }
    float bias = b[t * 16 + l15];
#pragma unroll
    for (int i = 0; i < 4; ++i) {
      float o = fmaxf(acc[i] + bias, 0.f);
      sm[(rt * 16 + quad * 4 + i) * CP + t * 16 + l15] = f2bf(o);
    }
  }
  __syncthreads();

  // ---- phase 3: segment-sum the 64 sorted rows, atomicAdd partials ----
  int f = tid & 127;
  int grp = tid >> 7;
  float run = 0.f;
  int cur = -1;
#pragma unroll
  for (int j = 0; j < 8; ++j) {
    int r = grp * 8 + j;
    int g = sbatch[r];
    if (g != cur) {
      if (cur >= 0) atomicAdd(&out[(size_t)cur * 128 + f], run);
      run = 0.f; cur = g;
    }
    if (g >= 0) run += bf2f(sm[r * CP + f]);
  }
  if (cur >= 0) atomicAdd(&out[(size_t)cur * 128 + f], run);
}

// divide pooled sums by segment counts
__global__ void k_finalize(float* __restrict__ out, const int* __restrict__ gstart, int G) {
  int idx = blockIdx.x * blockDim.x + threadIdx.x;
  if (idx >= G * 128) return;
  int g = idx >> 7;
  float cnt = (float)(gstart[g + 1] - gstart[g]);
  out[idx] = out[idx] / fmaxf(cnt, 1.f);
}

extern "C" void kernel_launch(void* const* d_in, const int* in_sizes, int n_in,
                              void* d_out, int out_size, void* d_ws, size_t ws_size,
                              hipStream_t stream) {
  const float* x  = (const float*)d_in[0];
  const int* ei   = (const int*)d_in[1];
  const int* batch = (const int*)d_in[2];
  const float* W1 = (const float*)d_in[3];
  const float* b1 = (const float*)d_in[4];
  const float* W2 = (const float*)d_in[5];
  const float* b2 = (const float*)d_in[6];
  const float* W3 = (const float*)d_in[7];
  const float* b3 = (const float*)d_in[8];
  float* out = (float*)d_out;
  int N = in_sizes[2];
  int E = in_sizes[1] / 2;
  int G = out_size / HD;
  const int* src = ei;
  const int* dst = ei + E;

  size_t off = 0;
  char* ws = (char*)d_ws;
  auto alloc = [&](size_t bytes) -> void* {
    void* p = ws + off;
    off += (bytes + 255) & ~(size_t)255;
    return p;
  };
  int nb1024 = (N + 1023) / 1024;
  int*   deg     = (int*)alloc((size_t)N * 4);        // N*4 is 256-aligned for N=200000
  int*   scanbuf = (int*)alloc((size_t)nb1024 * 4);   // contiguous after deg -> one memset
  float* dinv    = (float*)alloc((size_t)N * 4);
  int*   rowptr  = (int*)alloc((size_t)(N + 1) * 4);
  int*   eord    = (int*)alloc((size_t)E * 4);
  int*   col     = (int*)alloc((size_t)E * 4);
  int*   gstart  = (int*)alloc((size_t)(G + 1) * 4);
  unsigned short* xb  = (unsigned short*)alloc((size_t)N * 32 * 2);
  unsigned char*  hAq = (unsigned char*)alloc((size_t)N * 128);
  float*          hAs = (float*)alloc((size_t)N * 4);
  unsigned char*  hBq = (unsigned char*)alloc((size_t)N * 128);
  float*          hBs = (float*)alloc((size_t)N * 4);
  unsigned short* W1F = (unsigned short*)alloc(4096 * 2);
  unsigned short* W2F = (unsigned short*)alloc(16384 * 2);
  unsigned short* W3F = (unsigned short*)alloc(16384 * 2);
  (void)ws_size; (void)n_in;

  size_t zbytes = (size_t)((char*)dinv - (char*)deg);  // deg + scanbuf region
  hipMemsetAsync(deg, 0, zbytes, stream);
  k_degree<<<(E + 255) / 256, 256, 0, stream>>>(dst, deg, eord, E);
  k_scan<<<nb1024, 256, 0, stream>>>(deg, scanbuf, rowptr, dinv, N);

  int SB = (E + 255) / 256;
  int XB = (N * 32 + 255) / 256;
  int WB = 144;
  int BB = (N + 255) / 256;
  int ZB = (G * 32 + 255) / 256;   // out zero, float4/thread
  k_prep<<<SB + XB + WB + BB + ZB, 256, 0, stream>>>(src, dst, rowptr, eord, col, E,
                                                     x, dinv, xb, N,
                                                     W1, W2, W3, W1F, W2F, W3F,
                                                     batch, gstart, G, out,
                                                     SB, XB, WB, BB);

  int fusedBlocks = (N + 63) / 64;
  k_fused<32><<<fusedBlocks, 1024, 0, stream>>>(xb, nullptr, W1F, b1, rowptr, col, dinv,
                                                hAq, hAs, N);
  k_fused<128><<<fusedBlocks, 1024, 0, stream>>>(hAq, hAs, W2F, b2, rowptr, col, dinv,
                                                 hBq, hBs, N);
  k_fused_pool<<<fusedBlocks, 1024, 0, stream>>>(hBq, hBs, W3F, b3, rowptr, col, dinv,
                                                 batch, out, N);
  k_finalize<<<(G * 128 + 255) / 256, 256, 0, stream>>>(out, gstart, G);
}